// Round 11
// baseline (245.687 us; speedup 1.0000x reference)
//
#include <hip/hip_runtime.h>
#include <math.h>

#define N_TOTAL 32768
#define N0 8192
#define N1 1024
#define KNB 8
#define C_IN 128
#define C_H 64
#define COS_T 0.999f
#define NEG_INF -1e30f
#define GRID 512
#define BLOCK 512
#define NACT 384      // blocks that stay alive after stage 0
#define SLOT_DONE 0x7fffffffu

// sc1 agent-scope accessors (round-9 proven scheme): producers of cross-block
// data STORE write-through to the Infinity-Cache coherence point; consumers
// use PLAIN cached loads (each buffer is write-once-then-read this launch;
// dispatch start invalidates L2).
__device__ __forceinline__ void stc(float* p, float v) {
    __hip_atomic_store(p, v, __ATOMIC_RELAXED, __HIP_MEMORY_SCOPE_AGENT);
}
__device__ __forceinline__ void stci(int* p, int v) {
    __hip_atomic_store(p, v, __ATOMIC_RELAXED, __HIP_MEMORY_SCOPE_AGENT);
}
__device__ __forceinline__ float ldc(const float* p) {
    return __hip_atomic_load(p, __ATOMIC_RELAXED, __HIP_MEMORY_SCOPE_AGENT);
}

struct MegaParams {
    const float* feat;
    const float* xyz;
    const float* wsS[3];
    const float* bsS[3];
    const float* dgWs[3];
    const float* dgWn[3];
    const float* dgB[3];
    const float* dgH[3];
    const float* dgHb[3];
    const int* nb0;
    const int* ind0;
    const int* isc[2];
    float* out;
    float* xs0[4];
    float* xs1[4];
    float* xs2[4];
    float* s0;
    float* sbr;
    float* xyz0;
    float* featT;
    int* anchorA;
    int* anchorB;
    int* indb1; int* nbb1;
    int* indb2; int* nbb2;
    unsigned* slot;    // [GRID] per-block arrival slots (contiguous: 16 lines)
    int tr;
    int actCoh;
};

__global__ void __launch_bounds__(BLOCK, 4) mega_kernel(MegaParams P) {
    const int blk = blockIdx.x;
    const int tid = threadIdx.x;
    const int w = tid >> 6;      // wave id 0..7
    const int lane = tid & 63;   // channel

    __shared__ alignas(16) union {
        float tt[64][129];                                        // 33.0KB (transpose)
        struct { float wt[C_H * 132]; float col[16][C_IN]; } sp;  // 41.8KB (sphere)
        struct { float ws[C_H * 68]; float wn[C_H * 68];
                 float xw[16][C_H]; float aw[16][C_H]; } dg;      // 42.0KB (dgcn)
        struct { float sx[N1]; float sy[N1]; float sz[N1]; } tk;  // 12KB   (topk)
        float sc[N0];                                             // 32KB   (NMS)
    } u;
    __shared__ float rv[BLOCK];
    __shared__ int ri[BLOCK];
    __shared__ float psel[3];

    // Symmetric all-poll grid barrier (round 11): arrive = leader sc1-stores
    // slot[blk]=e; release = EVERY thread polls one slot (slot[tid] >= e).
    // No central coordinator, no flag hop: detection = last-arrival + one
    // poll period. Slots are contiguous (16 lines) -> polling is line-batched
    // (~1MB/grid/poll-cycle, throttled by s_sleep). Slot values are monotone;
    // exited blocks hold SLOT_DONE which satisfies every epoch.
    auto BAR = [&](int e) {
        asm volatile("s_waitcnt vmcnt(0)" ::: "memory");   // drain sc1 stores (per wave)
        __syncthreads();
        if (tid == 0)
            __hip_atomic_store(&P.slot[blk], (unsigned)e, __ATOMIC_RELAXED,
                               __HIP_MEMORY_SCOPE_AGENT);
        if (tid < GRID) {
            while (__hip_atomic_load(&P.slot[tid], __ATOMIC_RELAXED,
                                     __HIP_MEMORY_SCOPE_AGENT) < (unsigned)e)
                __builtin_amdgcn_s_sleep(4);
        }
        __syncthreads();
    };

    // ---- sphere: npb nodes/block; W^T staged wt[c*132+k] (b128 writes/reads).
    // ---- npb==16: 2 nodes/wave interleaved (shared W reads); npb==8: 1/wave.
    auto sphere = [&](int npb, int jb, const int* ind, const float* W,
                      const float* bv, float* xout) {
        __syncthreads();                          // union handoff
        const float4* W4 = (const float4*)W;
        for (int i4 = tid; i4 < C_H * C_IN / 4; i4 += BLOCK) {
            int c = i4 >> 5, kg = i4 & 31;        // granule stride 33: slot-distinct
            *(float4*)&u.sp.wt[c * 132 + kg * 4] = W4[i4];
        }
        __syncthreads();
        if (npb == 16) {
            const int j0 = jb + w, j1 = jb + 8 + w;
            const int p0 = ind[j0], p1 = ind[j1];
            if (P.tr) {
                u.sp.col[2 * w + 0][lane]      = P.featT[(size_t)p0 * C_IN + lane];
                u.sp.col[2 * w + 0][lane + 64] = P.featT[(size_t)p0 * C_IN + lane + 64];
                u.sp.col[2 * w + 1][lane]      = P.featT[(size_t)p1 * C_IN + lane];
                u.sp.col[2 * w + 1][lane + 64] = P.featT[(size_t)p1 * C_IN + lane + 64];
            } else {
                u.sp.col[2 * w + 0][lane]      = P.feat[(size_t)lane * N_TOTAL + p0];
                u.sp.col[2 * w + 0][lane + 64] = P.feat[(size_t)(lane + 64) * N_TOTAL + p0];
                u.sp.col[2 * w + 1][lane]      = P.feat[(size_t)lane * N_TOTAL + p1];
                u.sp.col[2 * w + 1][lane + 64] = P.feat[(size_t)(lane + 64) * N_TOTAL + p1];
            }
            float acc0 = bv[lane], acc1 = acc0;
#pragma unroll
            for (int k4 = 0; k4 < C_IN / 4; ++k4) {
                float4 c0 = *(const float4*)&u.sp.col[2 * w + 0][k4 * 4];
                float4 c1 = *(const float4*)&u.sp.col[2 * w + 1][k4 * 4];
                float4 wv = *(const float4*)&u.sp.wt[lane * 132 + k4 * 4];
                acc0 += c0.x * wv.x; acc1 += c1.x * wv.x;
                acc0 += c0.y * wv.y; acc1 += c1.y * wv.y;
                acc0 += c0.z * wv.z; acc1 += c1.z * wv.z;
                acc0 += c0.w * wv.w; acc1 += c1.w * wv.w;
            }
            stc(&xout[(size_t)j0 * C_H + lane], acc0);
            stc(&xout[(size_t)j1 * C_H + lane], acc1);
        } else {
            const int j = jb + w;
            const int p = ind[j];
            if (P.tr) {
                u.sp.col[w][lane]      = P.featT[(size_t)p * C_IN + lane];
                u.sp.col[w][lane + 64] = P.featT[(size_t)p * C_IN + lane + 64];
            } else {
                u.sp.col[w][lane]      = P.feat[(size_t)lane * N_TOTAL + p];
                u.sp.col[w][lane + 64] = P.feat[(size_t)(lane + 64) * N_TOTAL + p];
            }
            float acc = bv[lane];
#pragma unroll
            for (int k4 = 0; k4 < C_IN / 4; ++k4) {
                float4 cv = *(const float4*)&u.sp.col[w][k4 * 4];
                float4 wv = *(const float4*)&u.sp.wt[lane * 132 + k4 * 4];
                acc += cv.x * wv.x;
                acc += cv.y * wv.y;
                acc += cv.z * wv.z;
                acc += cv.w * wv.w;
            }
            stc(&xout[(size_t)j * C_H + lane], acc);
        }
    };

    // ---- one DGCN layer; weights staged c-major ws[c*68+k] via b128 writes.
    // ---- npb==16: 2 nodes/wave interleaved; npb==8: 1/wave.
    auto dgcn = [&](int npb, int jb, const float* xin, const int* nbp,
                    const float* Wsl, const float* Wnl, const float* bias, int l,
                    float* xout, bool last, const float* head, const float* hb,
                    float* sdst, float* odst) {
        __syncthreads();                          // union handoff
        const float* Ws_ = Wsl + l * C_H * C_H;
        const float* Wn_ = Wnl + l * C_H * C_H;
        {
            const int c = tid & 63;
            const int k0 = (tid >> 6) * 8;        // 512 threads cover 64c x 8 kgrp
            float v0, v1, v2, v3, v4, v5, v6, v7;
            v0 = Ws_[(k0 + 0) * C_H + c]; v1 = Ws_[(k0 + 1) * C_H + c];
            v2 = Ws_[(k0 + 2) * C_H + c]; v3 = Ws_[(k0 + 3) * C_H + c];
            v4 = Ws_[(k0 + 4) * C_H + c]; v5 = Ws_[(k0 + 5) * C_H + c];
            v6 = Ws_[(k0 + 6) * C_H + c]; v7 = Ws_[(k0 + 7) * C_H + c];
            *(float4*)&u.dg.ws[c * 68 + k0]     = make_float4(v0, v1, v2, v3);
            *(float4*)&u.dg.ws[c * 68 + k0 + 4] = make_float4(v4, v5, v6, v7);
            v0 = Wn_[(k0 + 0) * C_H + c]; v1 = Wn_[(k0 + 1) * C_H + c];
            v2 = Wn_[(k0 + 2) * C_H + c]; v3 = Wn_[(k0 + 3) * C_H + c];
            v4 = Wn_[(k0 + 4) * C_H + c]; v5 = Wn_[(k0 + 5) * C_H + c];
            v6 = Wn_[(k0 + 6) * C_H + c]; v7 = Wn_[(k0 + 7) * C_H + c];
            *(float4*)&u.dg.wn[c * 68 + k0]     = make_float4(v0, v1, v2, v3);
            *(float4*)&u.dg.wn[c * 68 + k0 + 4] = make_float4(v4, v5, v6, v7);
        }
        __syncthreads();
        if (npb == 16) {
            const int j0 = jb + w, j1 = jb + 8 + w;
            int q0[KNB], q1[KNB];
            float n0[KNB], n1[KNB];
#pragma unroll
            for (int t = 0; t < KNB; ++t) q0[t] = nbp[j0 * KNB + t];
#pragma unroll
            for (int t = 0; t < KNB; ++t) q1[t] = nbp[j1 * KNB + t];
            float xv0, xv1;
            if (!P.actCoh) {
                xv0 = xin[(size_t)j0 * C_H + lane];
                xv1 = xin[(size_t)j1 * C_H + lane];
#pragma unroll
                for (int t = 0; t < KNB; ++t) n0[t] = xin[(size_t)q0[t] * C_H + lane];
#pragma unroll
                for (int t = 0; t < KNB; ++t) n1[t] = xin[(size_t)q1[t] * C_H + lane];
            } else {
                xv0 = ldc(&xin[(size_t)j0 * C_H + lane]);
                xv1 = ldc(&xin[(size_t)j1 * C_H + lane]);
#pragma unroll
                for (int t = 0; t < KNB; ++t) n0[t] = ldc(&xin[(size_t)q0[t] * C_H + lane]);
#pragma unroll
                for (int t = 0; t < KNB; ++t) n1[t] = ldc(&xin[(size_t)q1[t] * C_H + lane]);
            }
            float a0 = 0.f, a1 = 0.f;
#pragma unroll
            for (int t = 0; t < KNB; ++t) a0 += n0[t];
#pragma unroll
            for (int t = 0; t < KNB; ++t) a1 += n1[t];
            u.dg.xw[2 * w + 0][lane] = xv0;
            u.dg.xw[2 * w + 1][lane] = xv1;
            u.dg.aw[2 * w + 0][lane] = a0 * (1.0f / KNB);
            u.dg.aw[2 * w + 1][lane] = a1 * (1.0f / KNB);
            // per-wave LDS slots: intra-wave ordering only
            float acc0 = bias[l * C_H + lane], acc1 = acc0;
#pragma unroll
            for (int k4 = 0; k4 < C_H / 4; ++k4) {
                float4 x0 = *(const float4*)&u.dg.xw[2 * w + 0][k4 * 4];
                float4 x1 = *(const float4*)&u.dg.xw[2 * w + 1][k4 * 4];
                float4 g0 = *(const float4*)&u.dg.aw[2 * w + 0][k4 * 4];
                float4 g1 = *(const float4*)&u.dg.aw[2 * w + 1][k4 * 4];
                float4 wsv = *(const float4*)&u.dg.ws[lane * 68 + k4 * 4];
                float4 wnv = *(const float4*)&u.dg.wn[lane * 68 + k4 * 4];
                acc0 += x0.x * wsv.x + g0.x * wnv.x;  acc1 += x1.x * wsv.x + g1.x * wnv.x;
                acc0 += x0.y * wsv.y + g0.y * wnv.y;  acc1 += x1.y * wsv.y + g1.y * wnv.y;
                acc0 += x0.z * wsv.z + g0.z * wnv.z;  acc1 += x1.z * wsv.z + g1.z * wnv.z;
                acc0 += x0.w * wsv.w + g0.w * wnv.w;  acc1 += x1.w * wsv.w + g1.w * wnv.w;
            }
            acc0 = fmaxf(acc0, 0.f);
            acc1 = fmaxf(acc1, 0.f);
            if (!last) {
                stc(&xout[(size_t)j0 * C_H + lane], acc0);
                stc(&xout[(size_t)j1 * C_H + lane], acc1);
            } else {
                float v0 = acc0 * head[lane];
                float v1 = acc1 * head[lane];
#pragma unroll
                for (int off = 32; off > 0; off >>= 1) {
                    v0 += __shfl_down(v0, off, 64);
                    v1 += __shfl_down(v1, off, 64);
                }
                if (lane == 0) {
                    float s0v = v0 + hb[0], s1v = v1 + hb[0];
                    if (sdst) { stc(&sdst[j0], s0v); stc(&sdst[j1], s1v); }
                    odst[j0] = 1.f / (1.f + expf(-s0v));   // flushed at kernel end
                    odst[j1] = 1.f / (1.f + expf(-s1v));
                }
            }
        } else {
            const int j = jb + w;
            float xv, a = 0.f;
            if (!P.actCoh) {
                xv = xin[(size_t)j * C_H + lane];
#pragma unroll
                for (int t = 0; t < KNB; ++t) {
                    int q = nbp[j * KNB + t];
                    a += xin[(size_t)q * C_H + lane];
                }
            } else {
                xv = ldc(&xin[(size_t)j * C_H + lane]);
#pragma unroll
                for (int t = 0; t < KNB; ++t) {
                    int q = nbp[j * KNB + t];
                    a += ldc(&xin[(size_t)q * C_H + lane]);
                }
            }
            u.dg.xw[w][lane] = xv;
            u.dg.aw[w][lane] = a * (1.0f / KNB);
            float acc = bias[l * C_H + lane];
#pragma unroll
            for (int k4 = 0; k4 < C_H / 4; ++k4) {
                float4 xv4 = *(const float4*)&u.dg.xw[w][k4 * 4];
                float4 av4 = *(const float4*)&u.dg.aw[w][k4 * 4];
                float4 wsv = *(const float4*)&u.dg.ws[lane * 68 + k4 * 4];
                float4 wnv = *(const float4*)&u.dg.wn[lane * 68 + k4 * 4];
                acc += xv4.x * wsv.x + av4.x * wnv.x;
                acc += xv4.y * wsv.y + av4.y * wnv.y;
                acc += xv4.z * wsv.z + av4.z * wnv.z;
                acc += xv4.w * wsv.w + av4.w * wnv.w;
            }
            acc = fmaxf(acc, 0.f);
            if (!last) {
                stc(&xout[(size_t)j * C_H + lane], acc);
            } else {
                float v = acc * head[lane];
#pragma unroll
                for (int off = 32; off > 0; off >>= 1) v += __shfl_down(v, off, 64);
                if (lane == 0) {
                    float s = v + hb[0];
                    if (sdst) stc(&sdst[j], s);
                    odst[j] = 1.f / (1.f + expf(-s));
                }
            }
        }
    };

    // ---- fused gather + per-row stable top-8; 8 rows/block (NACT blocks) ----
    auto topk = [&](const int* isc, const int* anc, int* indb, int* nbb) {
        __syncthreads();                          // union handoff
        const int b = blk >> 7;                   // branch (128 blocks per branch)
        const int a = anc[b];                     // plain (fresh line)
        const int* row = isc + (size_t)a * N1;
#pragma unroll
        for (int mm = 0; mm < 2; ++mm) {
            int m = mm * BLOCK + tid;
            int pp = row[m];
            u.tk.sx[m] = P.xyz[pp * 3 + 0];
            u.tk.sy[m] = P.xyz[pp * 3 + 1];
            u.tk.sz[m] = P.xyz[pp * 3 + 2];
        }
        if (tid < 8) {
            int grow = blk * 8 + tid;
            stci(&indb[grow], row[grow & (N1 - 1)]);
        }
        __syncthreads();
        {
            const int grow = blk * 8 + w;         // one row per wave
            const int r = grow & (N1 - 1);
            float rx = u.tk.sx[r], ry = u.tk.sy[r], rz = u.tk.sz[r];
            unsigned long long k[16];
#pragma unroll
            for (int t = 0; t < 16; ++t) {
                int m = t * 64 + lane;            // lane-consecutive: conflict-free
                float v = fabsf(rx * u.tk.sx[m] + ry * u.tk.sy[m] + rz * u.tk.sz[m]);
                k[t] = ((unsigned long long)__float_as_uint(v) << 32)
                     | (unsigned int)(0xFFFFFFFFu - (unsigned int)m);
            }
#pragma unroll
            for (int pass = 0; pass < KNB; ++pass) {
                unsigned long long lm = k[0];
#pragma unroll
                for (int t = 1; t < 16; ++t) lm = (k[t] > lm) ? k[t] : lm;
#pragma unroll
                for (int off = 1; off < 64; off <<= 1) {
                    unsigned long long o = __shfl_xor(lm, off, 64);
                    lm = (o > lm) ? o : lm;
                }
                if (lane == 0) {
                    int idx = (int)(0xFFFFFFFFu - (unsigned int)(lm & 0xFFFFFFFFull));
                    stci(&nbb[grow * KNB + pass], b * N1 + idx);
                }
#pragma unroll
                for (int t = 0; t < 16; ++t) if (k[t] == lm) k[t] = 0;
            }
        }
        // publish indb/nbb so this block's own plain reads see them
        asm volatile("s_waitcnt vmcnt(0)" ::: "memory");
        __syncthreads();
    };

    // ===== epoch 1: feat transpose (64 cols/block) + xyz0 gather =====
    if (P.tr) {
        const int g0 = blk * 64;
        const int col = tid & 63, rowH = tid >> 6;
        for (int c0 = 0; c0 < C_IN; c0 += 8) {
            int c = c0 + rowH;
            u.tt[col][c] = P.feat[(size_t)c * N_TOTAL + g0 + col];    // coalesced
        }
        __syncthreads();
        for (int i = tid; i < 64 * C_IN; i += BLOCK) {
            int cc = i >> 7, c = i & 127;
            stc(&P.featT[(size_t)(g0 + cc) * C_IN + c], u.tt[cc][c]); // coalesced
        }
    }
    if (tid < 16) {
        int j = blk * 16 + tid;
        int p = P.ind0[j];
        stc(&P.xyz0[j * 3 + 0], P.xyz[p * 3 + 0]);
        stc(&P.xyz0[j * 3 + 1], P.xyz[p * 3 + 1]);
        stc(&P.xyz0[j * 3 + 2], P.xyz[p * 3 + 2]);
    }
    BAR(1);

    // ===== stage 0 (16 nodes/block, all 512 blocks; 2 nodes/wave) =====
    const int jb0 = blk * 16;
    sphere(16, jb0, P.ind0, P.wsS[0], P.bsS[0], P.xs0[0]);
    BAR(2);
    dgcn(16, jb0, P.xs0[0], P.nb0, P.dgWs[0], P.dgWn[0], P.dgB[0], 0, P.xs0[1], false, nullptr, nullptr, nullptr, nullptr);
    BAR(3);
    dgcn(16, jb0, P.xs0[1], P.nb0, P.dgWs[0], P.dgWn[0], P.dgB[0], 1, P.xs0[2], false, nullptr, nullptr, nullptr, nullptr);
    BAR(4);
    dgcn(16, jb0, P.xs0[2], P.nb0, P.dgWs[0], P.dgWn[0], P.dgB[0], 2, P.xs0[3], false, nullptr, nullptr, nullptr, nullptr);
    BAR(5);
    dgcn(16, jb0, P.xs0[3], P.nb0, P.dgWs[0], P.dgWn[0], P.dgB[0], 3, nullptr, true,
         P.dgH[0], P.dgHb[0], P.s0, P.out);

    // blocks >= NACT: permanently satisfy their slot and exit
    if (blk >= NACT) {
        asm volatile("s_waitcnt vmcnt(0)" ::: "memory");
        __syncthreads();
        if (tid == 0)
            __hip_atomic_store(&P.slot[blk], SLOT_DONE, __ATOMIC_RELAXED,
                               __HIP_MEMORY_SCOPE_AGENT);
        return;
    }
    BAR(6);

    // ===== NMS (block 0 only; s0/xyz0 plain — fresh lines) =====
    if (blk == 0) {
        for (int jj = tid; jj < N0; jj += BLOCK) u.sc[jj] = P.s0[jj];
        __syncthreads();
        for (int it = 0; it < 3; ++it) {
            float bv = -INFINITY; int bi = 0x7fffffff;
            for (int jj = tid; jj < N0; jj += BLOCK) {
                float v = u.sc[jj];
                if (v > bv) { bv = v; bi = jj; }   // strided ascending: first max kept
            }
            rv[tid] = bv; ri[tid] = bi;
            __syncthreads();
            for (int sft = BLOCK / 2; sft > 0; sft >>= 1) {
                if (tid < sft) {
                    float v2 = rv[tid + sft]; int i2 = ri[tid + sft];
                    if (v2 > rv[tid] || (v2 == rv[tid] && i2 < ri[tid])) {
                        rv[tid] = v2; ri[tid] = i2;
                    }
                }
                __syncthreads();
            }
            int sel = ri[0];
            if (tid == 0) {
                stci(&P.anchorA[it], P.ind0[sel]);
                psel[0] = P.xyz0[sel * 3 + 0];
                psel[1] = P.xyz0[sel * 3 + 1];
                psel[2] = P.xyz0[sel * 3 + 2];
            }
            __syncthreads();
            float px = psel[0], py = psel[1], pz = psel[2];
            for (int jj = tid; jj < N0; jj += BLOCK) {
                float d = fabsf(P.xyz0[jj * 3 + 0] * px + P.xyz0[jj * 3 + 1] * py
                              + P.xyz0[jj * 3 + 2] * pz);
                if (d >= COS_T) u.sc[jj] = NEG_INF;
            }
            __syncthreads();
        }
    }
    BAR(7);

    // ===== stages 1 & 2 (384 blocks x 8 nodes; 1 node/wave) =====
    for (int st = 1; st <= 2; ++st) {
        float* const* xb = (st == 1) ? P.xs1 : P.xs2;
        int* indb = (st == 1) ? P.indb1 : P.indb2;
        int* nbb  = (st == 1) ? P.nbb1  : P.nbb2;
        const int* anc = (st == 1) ? P.anchorA : P.anchorB;
        const int ep = (st == 1) ? 7 : 13;
        const int jb12 = blk * 8;

        topk(P.isc[st - 1], anc, indb, nbb);
        sphere(8, jb12, indb, P.wsS[st], P.bsS[st], xb[0]);
        BAR(ep + 1);
        dgcn(8, jb12, xb[0], nbb, P.dgWs[st], P.dgWn[st], P.dgB[st], 0, xb[1], false, nullptr, nullptr, nullptr, nullptr);
        BAR(ep + 2);
        dgcn(8, jb12, xb[1], nbb, P.dgWs[st], P.dgWn[st], P.dgB[st], 1, xb[2], false, nullptr, nullptr, nullptr, nullptr);
        BAR(ep + 3);
        dgcn(8, jb12, xb[2], nbb, P.dgWs[st], P.dgWn[st], P.dgB[st], 2, xb[3], false, nullptr, nullptr, nullptr, nullptr);
        BAR(ep + 4);
        dgcn(8, jb12, xb[3], nbb, P.dgWs[st], P.dgWn[st], P.dgB[st], 3, nullptr, true,
             P.dgH[st], P.dgHb[st], (st == 1) ? P.sbr : nullptr,
             P.out + N0 + (st - 1) * 3 * N1);
        if (st == 1) {
            BAR(12);
            if (blk < 3) {    // per-branch argmax over sbr (plain, fresh)
                float bv = -INFINITY; int bi = 0x7fffffff;
                for (int m = tid; m < N1; m += BLOCK) {
                    float v = P.sbr[blk * N1 + m];
                    if (v > bv) { bv = v; bi = m; }   // ascending: first max kept
                }
                rv[tid] = bv; ri[tid] = bi;
                __syncthreads();
                for (int sft = BLOCK / 2; sft > 0; sft >>= 1) {
                    if (tid < sft) {
                        float v2 = rv[tid + sft]; int i2 = ri[tid + sft];
                        if (v2 > rv[tid] || (v2 == rv[tid] && i2 < ri[tid])) {
                            rv[tid] = v2; ri[tid] = i2;
                        }
                    }
                    __syncthreads();
                }
                if (tid == 0) stci(&P.anchorB[blk], P.indb1[blk * N1 + ri[0]]);
            }
            BAR(13);
        }
    }
}

extern "C" void kernel_launch(void* const* d_in, const int* in_sizes, int n_in,
                              void* d_out, int out_size, void* d_ws, size_t ws_size,
                              hipStream_t stream) {
    MegaParams hp;
    hp.feat = (const float*)d_in[0];
    hp.xyz  = (const float*)d_in[1];
    hp.wsS[0] = (const float*)d_in[2];  hp.bsS[0] = (const float*)d_in[3];
    hp.wsS[1] = (const float*)d_in[4];  hp.bsS[1] = (const float*)d_in[5];
    hp.wsS[2] = (const float*)d_in[6];  hp.bsS[2] = (const float*)d_in[7];
    hp.dgWs[0] = (const float*)d_in[8];  hp.dgWn[0] = (const float*)d_in[9];
    hp.dgB[0]  = (const float*)d_in[10]; hp.dgH[0]  = (const float*)d_in[11];
    hp.dgHb[0] = (const float*)d_in[12];
    hp.dgWs[1] = (const float*)d_in[13]; hp.dgWn[1] = (const float*)d_in[14];
    hp.dgB[1]  = (const float*)d_in[15]; hp.dgH[1]  = (const float*)d_in[16];
    hp.dgHb[1] = (const float*)d_in[17];
    hp.dgWs[2] = (const float*)d_in[18]; hp.dgWn[2] = (const float*)d_in[19];
    hp.dgB[2]  = (const float*)d_in[20]; hp.dgH[2]  = (const float*)d_in[21];
    hp.dgHb[2] = (const float*)d_in[22];
    const int* edge0 = (const int*)d_in[23];
    hp.nb0  = edge0 + N0 * KNB;
    hp.ind0 = (const int*)d_in[24];
    hp.isc[0] = (const int*)d_in[25];
    hp.isc[1] = (const int*)d_in[26];
    hp.out = (float*)d_out;

    float* f = (float*)d_ws;
    size_t o = 0;
    auto takeF = [&](size_t n) { float* p = f + o; o += n; return p; };

    hp.s0   = takeF(N0);
    hp.sbr  = takeF(3 * N1);
    hp.xyz0 = takeF((size_t)N0 * 3);
    o = (o + 63) & ~(size_t)63;
    hp.anchorA = (int*)takeF(64);
    hp.anchorB = (int*)takeF(64);
    hp.indb1 = (int*)takeF(3 * N1);
    hp.nbb1  = (int*)takeF(3 * N1 * KNB);
    hp.indb2 = (int*)takeF(3 * N1);
    hp.nbb2  = (int*)takeF(3 * N1 * KNB);
    o = (o + 63) & ~(size_t)63;
    hp.slot = (unsigned*)takeF(GRID);
    unsigned* ctrBase = hp.slot;

    size_t needFast = (o + 4 * (size_t)N0 * C_H + 8 * (size_t)(3 * N1) * C_H) * sizeof(float);
    if (ws_size >= needFast) {
        hp.actCoh = 0;
        for (int i = 0; i < 4; ++i) hp.xs0[i] = takeF((size_t)N0 * C_H);
        for (int i = 0; i < 4; ++i) hp.xs1[i] = takeF((size_t)(3 * N1) * C_H);
        for (int i = 0; i < 4; ++i) hp.xs2[i] = takeF((size_t)(3 * N1) * C_H);
    } else {
        hp.actCoh = 1;
        float* xA = takeF((size_t)N0 * C_H);
        float* xB = takeF((size_t)N0 * C_H);
        for (int i = 0; i < 4; ++i) {
            hp.xs0[i] = (i & 1) ? xB : xA;
            hp.xs1[i] = (i & 1) ? xB : xA;
            hp.xs2[i] = (i & 1) ? xB : xA;
        }
    }

    size_t needTr = (o + (size_t)N_TOTAL * C_IN) * sizeof(float);
    if (ws_size >= needTr) {
        hp.tr = 1;
        hp.featT = takeF((size_t)N_TOTAL * C_IN);
    } else {
        hp.tr = 0;
        hp.featT = nullptr;
    }

    hipMemsetAsync((void*)ctrBase, 0, GRID * sizeof(unsigned), stream);
    mega_kernel<<<dim3(GRID), dim3(BLOCK), 0, stream>>>(hp);
}

// Round 12
// 238.171 us; speedup vs baseline: 1.0316x; 1.0316x over previous
//
#include <hip/hip_runtime.h>
#include <math.h>

#define N_TOTAL 32768
#define N0 8192
#define N1 1024
#define KNB 8
#define C_IN 128
#define C_H 64
#define COS_T 0.999f
#define NEG_INF -1e30f
#define GRID 512
#define BLOCK 512
#define SLOT_DONE 0x7fffffffu

// Round-9 proven coherence: producers of CROSS-XCD data use sc1 write-through
// stores (visible at Infinity Cache); consumers use plain cached loads
// (buffers are write-once-then-read; dispatch start invalidates L2).
// NEW (round 12): stage-1/2 is branch<->XCD affine via runtime XCC_ID claim,
// so its buffers use PLAIN stores + PLAIN loads (producer and consumer share
// the same per-XCD L2 — no IC round trip at all).
__device__ __forceinline__ void stc(float* p, float v) {
    __hip_atomic_store(p, v, __ATOMIC_RELAXED, __HIP_MEMORY_SCOPE_AGENT);
}
__device__ __forceinline__ void stci(int* p, int v) {
    __hip_atomic_store(p, v, __ATOMIC_RELAXED, __HIP_MEMORY_SCOPE_AGENT);
}
__device__ __forceinline__ float ldc(const float* p) {
    return __hip_atomic_load(p, __ATOMIC_RELAXED, __HIP_MEMORY_SCOPE_AGENT);
}

struct MegaParams {
    const float* feat;
    const float* xyz;
    const float* wsS[3];
    const float* bsS[3];
    const float* dgWs[3];
    const float* dgWn[3];
    const float* dgB[3];
    const float* dgH[3];
    const float* dgHb[3];
    const int* nb0;
    const int* ind0;
    const int* isc[2];
    float* out;
    float* xs0[4];
    float* xs1[4];
    float* xs2[4];
    float* s0;
    float* sbr;
    float* xyz0;
    float* featT;
    int* anchorA;
    int* anchorB;
    int* indb1; int* nbb1;
    int* indb2; int* nbb2;
    unsigned* slot;    // [GRID] per-block arrival slots
    unsigned* flag;    // 8 replicated epoch lines (stride 16 words)
    unsigned* brCnt;   // [4] per-XCD rank counters
    int tr;
    int actCoh;
};

__global__ void __launch_bounds__(BLOCK, 4) mega_kernel(MegaParams P) {
    const int blk = blockIdx.x;
    const int tid = threadIdx.x;
    const int w = tid >> 6;      // wave id 0..7
    const int lane = tid & 63;   // channel

    __shared__ alignas(16) union {
        float tt[64][129];                                        // 33.0KB (transpose)
        struct { float wt[C_H * 132]; float col[16][C_IN]; } sp;  // 42.0KB (sphere)
        struct { float ws[C_H * 68]; float wn[C_H * 68];
                 float xw[16][C_H]; float aw[16][C_H]; } dg;      // 43.0KB (dgcn)
        struct { float sx[N1]; float sy[N1]; float sz[N1]; } tk;  // 12KB   (topk)
        float sc[N0];                                             // 32KB   (NMS)
    } u;
    // rv/ri oversized on purpose: total static LDS ~55.9KB forces <=2
    // blocks/CU; 512 co-resident blocks on 256 CUs => EXACTLY 2/CU =>
    // exactly 64 blocks per XCD (32 CUs/XCD) — required by the branch claim.
    __shared__ float rv[1600];
    __shared__ int ri[1600];
    __shared__ float psel[3];
    __shared__ int sXcd, sRank;

    // ---- runtime XCD claim: branch = XCC_ID (0..2 active), rank within XCD
    if (tid == 0) {
        unsigned xcd;
        asm volatile("s_getreg_b32 %0, hwreg(HW_REG_XCC_ID)" : "=s"(xcd));
        int r = -1;
        if (xcd < 3)
            r = (int)__hip_atomic_fetch_add(&P.brCnt[xcd], 1u, __ATOMIC_RELAXED,
                                            __HIP_MEMORY_SCOPE_AGENT);
        sXcd = (int)xcd; sRank = r;
    }
    __syncthreads();
    const int myBr = sXcd;
    const int myRank = sRank;
    const bool act12 = (myBr < 3) && (myRank >= 0) && (myRank < 64);

    // Round-9 two-hop barrier (proven best): leader sc1-stores slot[blk]=e;
    // block 0's threads poll slots in parallel; release via 8 replicated
    // flag lines. No cache-wide fences; caches stay warm.
    auto BAR = [&](int e) {
        asm volatile("s_waitcnt vmcnt(0)" ::: "memory");
        __syncthreads();
        if (blk == 0) {
            if (tid > 0 && tid < GRID) {
                while (__hip_atomic_load(&P.slot[tid], __ATOMIC_RELAXED,
                                         __HIP_MEMORY_SCOPE_AGENT) < (unsigned)e)
                    __builtin_amdgcn_s_sleep(1);
            }
            __syncthreads();
            if (tid < 8)
                __hip_atomic_store(&P.flag[tid * 16], (unsigned)e, __ATOMIC_RELAXED,
                                   __HIP_MEMORY_SCOPE_AGENT);
            __syncthreads();
        } else {
            if (tid == 0) {
                __hip_atomic_store(&P.slot[blk], (unsigned)e, __ATOMIC_RELAXED,
                                   __HIP_MEMORY_SCOPE_AGENT);
                while (__hip_atomic_load(&P.flag[(blk & 7) * 16], __ATOMIC_RELAXED,
                                         __HIP_MEMORY_SCOPE_AGENT) < (unsigned)e)
                    __builtin_amdgcn_s_sleep(2);
            }
            __syncthreads();
        }
    };

    // ---- sphere: 16 nodes/block (2/wave interleaved); coh: sc1 vs plain ----
    auto sphere = [&](int jb, const int* ind, const float* W,
                      const float* bv, float* xout, bool coh) {
        __syncthreads();                          // union handoff
        const float4* W4 = (const float4*)W;
        for (int i4 = tid; i4 < C_H * C_IN / 4; i4 += BLOCK) {
            int c = i4 >> 5, kg = i4 & 31;        // granule stride 33: slot-distinct
            *(float4*)&u.sp.wt[c * 132 + kg * 4] = W4[i4];
        }
        __syncthreads();
        const int j0 = jb + w, j1 = jb + 8 + w;
        const int p0 = ind[j0], p1 = ind[j1];
        if (P.tr) {
            u.sp.col[2 * w + 0][lane]      = P.featT[(size_t)p0 * C_IN + lane];
            u.sp.col[2 * w + 0][lane + 64] = P.featT[(size_t)p0 * C_IN + lane + 64];
            u.sp.col[2 * w + 1][lane]      = P.featT[(size_t)p1 * C_IN + lane];
            u.sp.col[2 * w + 1][lane + 64] = P.featT[(size_t)p1 * C_IN + lane + 64];
        } else {
            u.sp.col[2 * w + 0][lane]      = P.feat[(size_t)lane * N_TOTAL + p0];
            u.sp.col[2 * w + 0][lane + 64] = P.feat[(size_t)(lane + 64) * N_TOTAL + p0];
            u.sp.col[2 * w + 1][lane]      = P.feat[(size_t)lane * N_TOTAL + p1];
            u.sp.col[2 * w + 1][lane + 64] = P.feat[(size_t)(lane + 64) * N_TOTAL + p1];
        }
        float acc0 = bv[lane], acc1 = acc0;
#pragma unroll
        for (int k4 = 0; k4 < C_IN / 4; ++k4) {
            float4 c0 = *(const float4*)&u.sp.col[2 * w + 0][k4 * 4];
            float4 c1 = *(const float4*)&u.sp.col[2 * w + 1][k4 * 4];
            float4 wv = *(const float4*)&u.sp.wt[lane * 132 + k4 * 4];
            acc0 += c0.x * wv.x; acc1 += c1.x * wv.x;
            acc0 += c0.y * wv.y; acc1 += c1.y * wv.y;
            acc0 += c0.z * wv.z; acc1 += c1.z * wv.z;
            acc0 += c0.w * wv.w; acc1 += c1.w * wv.w;
        }
        if (coh) {
            stc(&xout[(size_t)j0 * C_H + lane], acc0);
            stc(&xout[(size_t)j1 * C_H + lane], acc1);
        } else {
            xout[(size_t)j0 * C_H + lane] = acc0;
            xout[(size_t)j1 * C_H + lane] = acc1;
        }
    };

    // ---- one DGCN layer: 16 nodes/block (2/wave, hoisted loads);
    // ---- weights staged c-major ws[c*68+k] via b128 writes ----
    auto dgcn = [&](int jb, const float* xin, const int* nbp,
                    const float* Wsl, const float* Wnl, const float* bias, int l,
                    float* xout, bool last, const float* head, const float* hb,
                    float* sdst, float* odst, bool coh) {
        __syncthreads();                          // union handoff
        const float* Ws_ = Wsl + l * C_H * C_H;
        const float* Wn_ = Wnl + l * C_H * C_H;
        {
            const int c = tid & 63;
            const int k0 = (tid >> 6) * 8;        // 512 threads cover 64c x 8 kgrp
            float v0, v1, v2, v3, v4, v5, v6, v7;
            v0 = Ws_[(k0 + 0) * C_H + c]; v1 = Ws_[(k0 + 1) * C_H + c];
            v2 = Ws_[(k0 + 2) * C_H + c]; v3 = Ws_[(k0 + 3) * C_H + c];
            v4 = Ws_[(k0 + 4) * C_H + c]; v5 = Ws_[(k0 + 5) * C_H + c];
            v6 = Ws_[(k0 + 6) * C_H + c]; v7 = Ws_[(k0 + 7) * C_H + c];
            *(float4*)&u.dg.ws[c * 68 + k0]     = make_float4(v0, v1, v2, v3);
            *(float4*)&u.dg.ws[c * 68 + k0 + 4] = make_float4(v4, v5, v6, v7);
            v0 = Wn_[(k0 + 0) * C_H + c]; v1 = Wn_[(k0 + 1) * C_H + c];
            v2 = Wn_[(k0 + 2) * C_H + c]; v3 = Wn_[(k0 + 3) * C_H + c];
            v4 = Wn_[(k0 + 4) * C_H + c]; v5 = Wn_[(k0 + 5) * C_H + c];
            v6 = Wn_[(k0 + 6) * C_H + c]; v7 = Wn_[(k0 + 7) * C_H + c];
            *(float4*)&u.dg.wn[c * 68 + k0]     = make_float4(v0, v1, v2, v3);
            *(float4*)&u.dg.wn[c * 68 + k0 + 4] = make_float4(v4, v5, v6, v7);
        }
        __syncthreads();
        const int j0 = jb + w, j1 = jb + 8 + w;
        int q0[KNB], q1[KNB];
        float n0[KNB], n1[KNB];
#pragma unroll
        for (int t = 0; t < KNB; ++t) q0[t] = nbp[j0 * KNB + t];
#pragma unroll
        for (int t = 0; t < KNB; ++t) q1[t] = nbp[j1 * KNB + t];
        float xv0, xv1;
        if (!P.actCoh) {
            xv0 = xin[(size_t)j0 * C_H + lane];
            xv1 = xin[(size_t)j1 * C_H + lane];
#pragma unroll
            for (int t = 0; t < KNB; ++t) n0[t] = xin[(size_t)q0[t] * C_H + lane];
#pragma unroll
            for (int t = 0; t < KNB; ++t) n1[t] = xin[(size_t)q1[t] * C_H + lane];
        } else {
            xv0 = ldc(&xin[(size_t)j0 * C_H + lane]);
            xv1 = ldc(&xin[(size_t)j1 * C_H + lane]);
#pragma unroll
            for (int t = 0; t < KNB; ++t) n0[t] = ldc(&xin[(size_t)q0[t] * C_H + lane]);
#pragma unroll
            for (int t = 0; t < KNB; ++t) n1[t] = ldc(&xin[(size_t)q1[t] * C_H + lane]);
        }
        float a0 = 0.f, a1 = 0.f;
#pragma unroll
        for (int t = 0; t < KNB; ++t) a0 += n0[t];
#pragma unroll
        for (int t = 0; t < KNB; ++t) a1 += n1[t];
        u.dg.xw[2 * w + 0][lane] = xv0;
        u.dg.xw[2 * w + 1][lane] = xv1;
        u.dg.aw[2 * w + 0][lane] = a0 * (1.0f / KNB);
        u.dg.aw[2 * w + 1][lane] = a1 * (1.0f / KNB);
        // per-wave LDS slots: intra-wave ordering only
        float acc0 = bias[l * C_H + lane], acc1 = acc0;
#pragma unroll
        for (int k4 = 0; k4 < C_H / 4; ++k4) {
            float4 x0 = *(const float4*)&u.dg.xw[2 * w + 0][k4 * 4];
            float4 x1 = *(const float4*)&u.dg.xw[2 * w + 1][k4 * 4];
            float4 g0 = *(const float4*)&u.dg.aw[2 * w + 0][k4 * 4];
            float4 g1 = *(const float4*)&u.dg.aw[2 * w + 1][k4 * 4];
            float4 wsv = *(const float4*)&u.dg.ws[lane * 68 + k4 * 4];
            float4 wnv = *(const float4*)&u.dg.wn[lane * 68 + k4 * 4];
            acc0 += x0.x * wsv.x + g0.x * wnv.x;  acc1 += x1.x * wsv.x + g1.x * wnv.x;
            acc0 += x0.y * wsv.y + g0.y * wnv.y;  acc1 += x1.y * wsv.y + g1.y * wnv.y;
            acc0 += x0.z * wsv.z + g0.z * wnv.z;  acc1 += x1.z * wsv.z + g1.z * wnv.z;
            acc0 += x0.w * wsv.w + g0.w * wnv.w;  acc1 += x1.w * wsv.w + g1.w * wnv.w;
        }
        acc0 = fmaxf(acc0, 0.f);
        acc1 = fmaxf(acc1, 0.f);
        if (!last) {
            if (coh) {
                stc(&xout[(size_t)j0 * C_H + lane], acc0);
                stc(&xout[(size_t)j1 * C_H + lane], acc1);
            } else {
                xout[(size_t)j0 * C_H + lane] = acc0;
                xout[(size_t)j1 * C_H + lane] = acc1;
            }
        } else {
            float v0 = acc0 * head[lane];
            float v1 = acc1 * head[lane];
#pragma unroll
            for (int off = 32; off > 0; off >>= 1) {
                v0 += __shfl_down(v0, off, 64);
                v1 += __shfl_down(v1, off, 64);
            }
            if (lane == 0) {
                float s0v = v0 + hb[0], s1v = v1 + hb[0];
                if (sdst) {
                    if (coh) { stc(&sdst[j0], s0v); stc(&sdst[j1], s1v); }
                    else     { sdst[j0] = s0v; sdst[j1] = s1v; }
                }
                odst[j0] = 1.f / (1.f + expf(-s0v));   // flushed at kernel end
                odst[j1] = 1.f / (1.f + expf(-s1v));
            }
        }
    };

    // ---- fused gather + per-row stable top-8; 16 rows/block, branch-local,
    // ---- PLAIN stores (same-XCD consumers) ----
    auto topk = [&](const int* isc, const int* anc, int* indb, int* nbb,
                    int br, int sl) {
        __syncthreads();                          // union handoff
        const int a = anc[br];
        const int* row = isc + (size_t)a * N1;
#pragma unroll
        for (int mm = 0; mm < 2; ++mm) {
            int m = mm * BLOCK + tid;
            int pp = row[m];
            u.tk.sx[m] = P.xyz[pp * 3 + 0];
            u.tk.sy[m] = P.xyz[pp * 3 + 1];
            u.tk.sz[m] = P.xyz[pp * 3 + 2];
        }
        if (tid < 16) {
            int r = sl * 16 + tid;
            indb[br * N1 + r] = row[r];
        }
        __syncthreads();
#pragma unroll
        for (int rr = 0; rr < 2; ++rr) {
            const int r = sl * 16 + rr * 8 + w;   // branch-local row
            const int grow = br * N1 + r;
            float rx = u.tk.sx[r], ry = u.tk.sy[r], rz = u.tk.sz[r];
            unsigned long long k[16];
#pragma unroll
            for (int t = 0; t < 16; ++t) {
                int m = t * 64 + lane;            // lane-consecutive: conflict-free
                float v = fabsf(rx * u.tk.sx[m] + ry * u.tk.sy[m] + rz * u.tk.sz[m]);
                k[t] = ((unsigned long long)__float_as_uint(v) << 32)
                     | (unsigned int)(0xFFFFFFFFu - (unsigned int)m);
            }
#pragma unroll
            for (int pass = 0; pass < KNB; ++pass) {
                unsigned long long lm = k[0];
#pragma unroll
                for (int t = 1; t < 16; ++t) lm = (k[t] > lm) ? k[t] : lm;
#pragma unroll
                for (int off = 1; off < 64; off <<= 1) {
                    unsigned long long o = __shfl_xor(lm, off, 64);
                    lm = (o > lm) ? o : lm;
                }
                if (lane == 0) {
                    int idx = (int)(0xFFFFFFFFu - (unsigned int)(lm & 0xFFFFFFFFull));
                    nbb[grow * KNB + pass] = br * N1 + idx;
                }
#pragma unroll
                for (int t = 0; t < 16; ++t) if (k[t] == lm) k[t] = 0;
            }
        }
        // publish indb/nbb (to L2) for this block's own sphere reads
        asm volatile("s_waitcnt vmcnt(0)" ::: "memory");
        __syncthreads();
    };

    // ===== epoch 1: feat transpose (64 cols/block) + xyz0 gather =====
    if (P.tr) {
        const int g0 = blk * 64;
        const int col = tid & 63, rowH = tid >> 6;
        for (int c0 = 0; c0 < C_IN; c0 += 8) {
            int c = c0 + rowH;
            u.tt[col][c] = P.feat[(size_t)c * N_TOTAL + g0 + col];    // coalesced
        }
        __syncthreads();
        for (int i = tid; i < 64 * C_IN; i += BLOCK) {
            int cc = i >> 7, c = i & 127;
            stc(&P.featT[(size_t)(g0 + cc) * C_IN + c], u.tt[cc][c]); // coalesced
        }
    }
    if (tid < 16) {
        int j = blk * 16 + tid;
        int p = P.ind0[j];
        stc(&P.xyz0[j * 3 + 0], P.xyz[p * 3 + 0]);
        stc(&P.xyz0[j * 3 + 1], P.xyz[p * 3 + 1]);
        stc(&P.xyz0[j * 3 + 2], P.xyz[p * 3 + 2]);
    }
    BAR(1);

    // ===== stage 0 (16 nodes/block, all 512 blocks; 2 nodes/wave; sc1) =====
    const int jb0 = blk * 16;
    sphere(jb0, P.ind0, P.wsS[0], P.bsS[0], P.xs0[0], true);
    BAR(2);
    dgcn(jb0, P.xs0[0], P.nb0, P.dgWs[0], P.dgWn[0], P.dgB[0], 0, P.xs0[1], false, nullptr, nullptr, nullptr, nullptr, true);
    BAR(3);
    dgcn(jb0, P.xs0[1], P.nb0, P.dgWs[0], P.dgWn[0], P.dgB[0], 1, P.xs0[2], false, nullptr, nullptr, nullptr, nullptr, true);
    BAR(4);
    dgcn(jb0, P.xs0[2], P.nb0, P.dgWs[0], P.dgWn[0], P.dgB[0], 2, P.xs0[3], false, nullptr, nullptr, nullptr, nullptr, true);
    BAR(5);
    dgcn(jb0, P.xs0[3], P.nb0, P.dgWs[0], P.dgWn[0], P.dgB[0], 3, nullptr, true,
         P.dgH[0], P.dgHb[0], P.s0, P.out, true);

    // blocks not needed for stage 1/2 (and not the coordinator): exit
    if (!act12 && blk != 0) {
        asm volatile("s_waitcnt vmcnt(0)" ::: "memory");
        __syncthreads();
        if (tid == 0)
            __hip_atomic_store(&P.slot[blk], SLOT_DONE, __ATOMIC_RELAXED,
                               __HIP_MEMORY_SCOPE_AGENT);
        return;
    }
    BAR(6);

    // ===== NMS (block 0 only; s0/xyz0 plain — fresh lines) =====
    if (blk == 0) {
        for (int jj = tid; jj < N0; jj += BLOCK) u.sc[jj] = P.s0[jj];
        __syncthreads();
        for (int it = 0; it < 3; ++it) {
            float bv = -INFINITY; int bi = 0x7fffffff;
            for (int jj = tid; jj < N0; jj += BLOCK) {
                float v = u.sc[jj];
                if (v > bv) { bv = v; bi = jj; }   // strided ascending: first max kept
            }
            rv[tid] = bv; ri[tid] = bi;
            __syncthreads();
            for (int sft = BLOCK / 2; sft > 0; sft >>= 1) {
                if (tid < sft) {
                    float v2 = rv[tid + sft]; int i2 = ri[tid + sft];
                    if (v2 > rv[tid] || (v2 == rv[tid] && i2 < ri[tid])) {
                        rv[tid] = v2; ri[tid] = i2;
                    }
                }
                __syncthreads();
            }
            int sel = ri[0];
            if (tid == 0) {
                stci(&P.anchorA[it], P.ind0[sel]);
                psel[0] = P.xyz0[sel * 3 + 0];
                psel[1] = P.xyz0[sel * 3 + 1];
                psel[2] = P.xyz0[sel * 3 + 2];
            }
            __syncthreads();
            float px = psel[0], py = psel[1], pz = psel[2];
            for (int jj = tid; jj < N0; jj += BLOCK) {
                float d = fabsf(P.xyz0[jj * 3 + 0] * px + P.xyz0[jj * 3 + 1] * py
                              + P.xyz0[jj * 3 + 2] * pz);
                if (d >= COS_T) u.sc[jj] = NEG_INF;
            }
            __syncthreads();
        }
    }
    BAR(7);

    // ===== stages 1 & 2: branch b on XCD b, 64 blocks x 16 nodes.
    // ===== All buffers PLAIN (same-XCD producer/consumer). =====
    const int jb12 = act12 ? (myBr * N1 + myRank * 16) : 0;
    const bool coh12 = (P.actCoh != 0);   // fallback: aliased buffers need sc1

    for (int st = 1; st <= 2; ++st) {
        float* const* xb = (st == 1) ? P.xs1 : P.xs2;
        int* indb = (st == 1) ? P.indb1 : P.indb2;
        int* nbb  = (st == 1) ? P.nbb1  : P.nbb2;
        const int* anc = (st == 1) ? P.anchorA : P.anchorB;
        const int ep = (st == 1) ? 7 : 13;

        if (act12) {
            topk(P.isc[st - 1], anc, indb, nbb, myBr, myRank);
            sphere(jb12, indb, P.wsS[st], P.bsS[st], xb[0], coh12);
        }
        BAR(ep + 1);
        if (act12) dgcn(jb12, xb[0], nbb, P.dgWs[st], P.dgWn[st], P.dgB[st], 0, xb[1], false, nullptr, nullptr, nullptr, nullptr, coh12);
        BAR(ep + 2);
        if (act12) dgcn(jb12, xb[1], nbb, P.dgWs[st], P.dgWn[st], P.dgB[st], 1, xb[2], false, nullptr, nullptr, nullptr, nullptr, coh12);
        BAR(ep + 3);
        if (act12) dgcn(jb12, xb[2], nbb, P.dgWs[st], P.dgWn[st], P.dgB[st], 2, xb[3], false, nullptr, nullptr, nullptr, nullptr, coh12);
        BAR(ep + 4);
        if (act12) dgcn(jb12, xb[3], nbb, P.dgWs[st], P.dgWn[st], P.dgB[st], 3, nullptr, true,
                        P.dgH[st], P.dgHb[st], (st == 1) ? P.sbr : nullptr,
                        P.out + N0 + (st - 1) * 3 * N1, coh12);
        if (st == 1) {
            BAR(12);
            if (act12 && myRank == 0) {   // per-branch argmax, same XCD as writers
                float bv = -INFINITY; int bi = 0x7fffffff;
                for (int m = tid; m < N1; m += BLOCK) {
                    float v = P.sbr[myBr * N1 + m];
                    if (v > bv) { bv = v; bi = m; }   // ascending: first max kept
                }
                rv[tid] = bv; ri[tid] = bi;
                __syncthreads();
                for (int sft = BLOCK / 2; sft > 0; sft >>= 1) {
                    if (tid < sft) {
                        float v2 = rv[tid + sft]; int i2 = ri[tid + sft];
                        if (v2 > rv[tid] || (v2 == rv[tid] && i2 < ri[tid])) {
                            rv[tid] = v2; ri[tid] = i2;
                        }
                    }
                    __syncthreads();
                }
                if (tid == 0) P.anchorB[myBr] = P.indb1[myBr * N1 + ri[0]];
            }
            BAR(13);
        }
    }
}

extern "C" void kernel_launch(void* const* d_in, const int* in_sizes, int n_in,
                              void* d_out, int out_size, void* d_ws, size_t ws_size,
                              hipStream_t stream) {
    MegaParams hp;
    hp.feat = (const float*)d_in[0];
    hp.xyz  = (const float*)d_in[1];
    hp.wsS[0] = (const float*)d_in[2];  hp.bsS[0] = (const float*)d_in[3];
    hp.wsS[1] = (const float*)d_in[4];  hp.bsS[1] = (const float*)d_in[5];
    hp.wsS[2] = (const float*)d_in[6];  hp.bsS[2] = (const float*)d_in[7];
    hp.dgWs[0] = (const float*)d_in[8];  hp.dgWn[0] = (const float*)d_in[9];
    hp.dgB[0]  = (const float*)d_in[10]; hp.dgH[0]  = (const float*)d_in[11];
    hp.dgHb[0] = (const float*)d_in[12];
    hp.dgWs[1] = (const float*)d_in[13]; hp.dgWn[1] = (const float*)d_in[14];
    hp.dgB[1]  = (const float*)d_in[15]; hp.dgH[1]  = (const float*)d_in[16];
    hp.dgHb[1] = (const float*)d_in[17];
    hp.dgWs[2] = (const float*)d_in[18]; hp.dgWn[2] = (const float*)d_in[19];
    hp.dgB[2]  = (const float*)d_in[20]; hp.dgH[2]  = (const float*)d_in[21];
    hp.dgHb[2] = (const float*)d_in[22];
    const int* edge0 = (const int*)d_in[23];
    hp.nb0  = edge0 + N0 * KNB;
    hp.ind0 = (const int*)d_in[24];
    hp.isc[0] = (const int*)d_in[25];
    hp.isc[1] = (const int*)d_in[26];
    hp.out = (float*)d_out;

    float* f = (float*)d_ws;
    size_t o = 0;
    auto takeF = [&](size_t n) { float* p = f + o; o += n; return p; };

    hp.s0   = takeF(N0);
    hp.sbr  = takeF(3 * N1);
    hp.xyz0 = takeF((size_t)N0 * 3);
    o = (o + 63) & ~(size_t)63;
    hp.anchorA = (int*)takeF(64);
    hp.anchorB = (int*)takeF(64);
    hp.indb1 = (int*)takeF(3 * N1);
    hp.nbb1  = (int*)takeF(3 * N1 * KNB);
    hp.indb2 = (int*)takeF(3 * N1);
    hp.nbb2  = (int*)takeF(3 * N1 * KNB);
    o = (o + 63) & ~(size_t)63;
    hp.slot  = (unsigned*)takeF(GRID);       // 512 slots
    hp.flag  = (unsigned*)takeF(8 * 16);     // 8 replicated flag lines
    hp.brCnt = (unsigned*)takeF(16);         // 4 per-XCD rank counters (+pad)
    unsigned* ctrBase = hp.slot;
    size_t ctrWords = GRID + 8 * 16 + 16;

    size_t needFast = (o + 4 * (size_t)N0 * C_H + 8 * (size_t)(3 * N1) * C_H) * sizeof(float);
    if (ws_size >= needFast) {
        hp.actCoh = 0;
        for (int i = 0; i < 4; ++i) hp.xs0[i] = takeF((size_t)N0 * C_H);
        for (int i = 0; i < 4; ++i) hp.xs1[i] = takeF((size_t)(3 * N1) * C_H);
        for (int i = 0; i < 4; ++i) hp.xs2[i] = takeF((size_t)(3 * N1) * C_H);
    } else {
        hp.actCoh = 1;
        float* xA = takeF((size_t)N0 * C_H);
        float* xB = takeF((size_t)N0 * C_H);
        for (int i = 0; i < 4; ++i) {
            hp.xs0[i] = (i & 1) ? xB : xA;
            hp.xs1[i] = (i & 1) ? xB : xA;
            hp.xs2[i] = (i & 1) ? xB : xA;
        }
    }

    size_t needTr = (o + (size_t)N_TOTAL * C_IN) * sizeof(float);
    if (ws_size >= needTr) {
        hp.tr = 1;
        hp.featT = takeF((size_t)N_TOTAL * C_IN);
    } else {
        hp.tr = 0;
        hp.featT = nullptr;
    }

    hipMemsetAsync((void*)ctrBase, 0, ctrWords * sizeof(unsigned), stream);
    mega_kernel<<<dim3(GRID), dim3(BLOCK), 0, stream>>>(hp);
}

// Round 13
// 174.440 us; speedup vs baseline: 1.4084x; 1.3653x over previous
//
#include <hip/hip_runtime.h>
#include <math.h>

#define N_TOTAL 32768
#define N0 8192
#define N1 1024
#define KNB 8
#define C_IN 128
#define C_H 64
#define COS_T 0.999f
#define NEG_INF -1e30f
#define GRID 512
#define BLOCK 512
#define NACT 384      // blocks that stay alive after stage 0
#define SLOT_DONE 0x7fffffffu

// sc1 agent-scope accessors: write-through to the Infinity-Cache coherence
// point. Producers of cross-block data STORE with these; consumers use PLAIN
// cached loads (safe: each buffer is written-once-then-read in this launch;
// dispatch start invalidates L2 — proven rounds 4-9; alternatives measured
// worse: L2-wb fences (r10, +63us), all-poll barrier (r11, +72us),
// XCD-affine plain stores (r8/r12, +55-65us)).
__device__ __forceinline__ void stc(float* p, float v) {
    __hip_atomic_store(p, v, __ATOMIC_RELAXED, __HIP_MEMORY_SCOPE_AGENT);
}
__device__ __forceinline__ void stci(int* p, int v) {
    __hip_atomic_store(p, v, __ATOMIC_RELAXED, __HIP_MEMORY_SCOPE_AGENT);
}
__device__ __forceinline__ float ldc(const float* p) {
    return __hip_atomic_load(p, __ATOMIC_RELAXED, __HIP_MEMORY_SCOPE_AGENT);
}

struct MegaParams {
    const float* feat;
    const float* xyz;
    const float* wsS[3];
    const float* bsS[3];
    const float* dgWs[3];
    const float* dgWn[3];
    const float* dgB[3];
    const float* dgH[3];
    const float* dgHb[3];
    const int* nb0;
    const int* ind0;
    const int* isc[2];
    float* out;
    float* xs0[4];
    float* xs1[4];
    float* xs2[4];
    float* s0;
    float* sbr;
    float* xyz0;
    float* featT;
    int* anchorA;
    int* anchorB;
    int* indb1; int* nbb1;
    int* indb2; int* nbb2;
    unsigned* slot;    // [GRID] per-block arrival slots
    unsigned* flag;    // 8 replicated epoch lines (stride 16 words)
    int tr;
    int actCoh;
};

__global__ void __launch_bounds__(BLOCK, 4) mega_kernel(MegaParams P) {
    const int blk = blockIdx.x;
    const int tid = threadIdx.x;
    const int w = tid >> 6;      // wave id 0..7
    const int lane = tid & 63;   // channel

    __shared__ alignas(16) union {
        float tt[64][129];                                        // 33.0KB (transpose)
        struct { float wt[C_H * 132]; float col[16][C_IN]; } sp;  // 41.8KB (sphere)
        struct { float ws[C_H * 68]; float wn[C_H * 68];
                 float xw[16][C_H]; float aw[16][C_H]; } dg;      // 42.0KB (dgcn)
        struct { float sx[N1]; float sy[N1]; float sz[N1]; } tk;  // 12KB   (topk)
        float sc[N0];                                             // 32KB   (NMS)
    } u;
    __shared__ float rv[BLOCK];
    __shared__ int ri[BLOCK];
    __shared__ float psel[3];

    // Contention-free two-hop grid barrier (round-7/9 proven): per-block slot
    // store, block 0 polls slots in parallel, releases via 8 replicated flag
    // lines. No cache-wide fences; caches stay warm.
    auto BAR = [&](int e) {
        asm volatile("s_waitcnt vmcnt(0)" ::: "memory");
        __syncthreads();
        if (blk == 0) {
            if (tid > 0 && tid < GRID) {
                while (__hip_atomic_load(&P.slot[tid], __ATOMIC_RELAXED,
                                         __HIP_MEMORY_SCOPE_AGENT) < (unsigned)e)
                    __builtin_amdgcn_s_sleep(1);
            }
            __syncthreads();
            if (tid < 8)
                __hip_atomic_store(&P.flag[tid * 16], (unsigned)e, __ATOMIC_RELAXED,
                                   __HIP_MEMORY_SCOPE_AGENT);
            __syncthreads();
        } else {
            if (tid == 0) {
                __hip_atomic_store(&P.slot[blk], (unsigned)e, __ATOMIC_RELAXED,
                                   __HIP_MEMORY_SCOPE_AGENT);
                while (__hip_atomic_load(&P.flag[(blk & 7) * 16], __ATOMIC_RELAXED,
                                         __HIP_MEMORY_SCOPE_AGENT) < (unsigned)e)
                    __builtin_amdgcn_s_sleep(2);
            }
            __syncthreads();
        }
    };

    // ---- sphere: npb nodes/block; W^T staged wt[c*132+k] (b128 writes/reads).
    // ---- npb==16: 2 nodes/wave interleaved (shared W reads); npb==8: 1/wave.
    auto sphere = [&](int npb, int jb, const int* ind, const float* W,
                      const float* bv, float* xout) {
        __syncthreads();                          // union handoff
        const float4* W4 = (const float4*)W;
        for (int i4 = tid; i4 < C_H * C_IN / 4; i4 += BLOCK) {
            int c = i4 >> 5, kg = i4 & 31;        // granule stride 33: slot-distinct
            *(float4*)&u.sp.wt[c * 132 + kg * 4] = W4[i4];
        }
        __syncthreads();
        if (npb == 16) {
            const int j0 = jb + w, j1 = jb + 8 + w;
            const int p0 = ind[j0], p1 = ind[j1];
            if (P.tr) {
                u.sp.col[2 * w + 0][lane]      = P.featT[(size_t)p0 * C_IN + lane];
                u.sp.col[2 * w + 0][lane + 64] = P.featT[(size_t)p0 * C_IN + lane + 64];
                u.sp.col[2 * w + 1][lane]      = P.featT[(size_t)p1 * C_IN + lane];
                u.sp.col[2 * w + 1][lane + 64] = P.featT[(size_t)p1 * C_IN + lane + 64];
            } else {
                u.sp.col[2 * w + 0][lane]      = P.feat[(size_t)lane * N_TOTAL + p0];
                u.sp.col[2 * w + 0][lane + 64] = P.feat[(size_t)(lane + 64) * N_TOTAL + p0];
                u.sp.col[2 * w + 1][lane]      = P.feat[(size_t)lane * N_TOTAL + p1];
                u.sp.col[2 * w + 1][lane + 64] = P.feat[(size_t)(lane + 64) * N_TOTAL + p1];
            }
            float acc0 = bv[lane], acc1 = acc0;
#pragma unroll
            for (int k4 = 0; k4 < C_IN / 4; ++k4) {
                float4 c0 = *(const float4*)&u.sp.col[2 * w + 0][k4 * 4];
                float4 c1 = *(const float4*)&u.sp.col[2 * w + 1][k4 * 4];
                float4 wv = *(const float4*)&u.sp.wt[lane * 132 + k4 * 4];
                acc0 += c0.x * wv.x; acc1 += c1.x * wv.x;
                acc0 += c0.y * wv.y; acc1 += c1.y * wv.y;
                acc0 += c0.z * wv.z; acc1 += c1.z * wv.z;
                acc0 += c0.w * wv.w; acc1 += c1.w * wv.w;
            }
            stc(&xout[(size_t)j0 * C_H + lane], acc0);
            stc(&xout[(size_t)j1 * C_H + lane], acc1);
        } else {
            const int j = jb + w;
            const int p = ind[j];
            if (P.tr) {
                u.sp.col[w][lane]      = P.featT[(size_t)p * C_IN + lane];
                u.sp.col[w][lane + 64] = P.featT[(size_t)p * C_IN + lane + 64];
            } else {
                u.sp.col[w][lane]      = P.feat[(size_t)lane * N_TOTAL + p];
                u.sp.col[w][lane + 64] = P.feat[(size_t)(lane + 64) * N_TOTAL + p];
            }
            float acc = bv[lane];
#pragma unroll
            for (int k4 = 0; k4 < C_IN / 4; ++k4) {
                float4 cv = *(const float4*)&u.sp.col[w][k4 * 4];
                float4 wv = *(const float4*)&u.sp.wt[lane * 132 + k4 * 4];
                acc += cv.x * wv.x;
                acc += cv.y * wv.y;
                acc += cv.z * wv.z;
                acc += cv.w * wv.w;
            }
            stc(&xout[(size_t)j * C_H + lane], acc);
        }
    };

    // ---- one DGCN layer; weights staged c-major ws[c*68+k] via b128 writes
    // ---- (8 coalesced global loads -> 2 ds_write_b128: conflict-free).
    // ---- npb==16: 2 nodes/wave interleaved; npb==8: 1/wave.
    auto dgcn = [&](int npb, int jb, const float* xin, const int* nbp,
                    const float* Wsl, const float* Wnl, const float* bias, int l,
                    float* xout, bool last, const float* head, const float* hb,
                    float* sdst, float* odst) {
        __syncthreads();                          // union handoff
        const float* Ws_ = Wsl + l * C_H * C_H;
        const float* Wn_ = Wnl + l * C_H * C_H;
        {
            const int c = tid & 63;
            const int k0 = (tid >> 6) * 8;        // 512 threads cover 64c x 8 kgrp
            float v0, v1, v2, v3, v4, v5, v6, v7;
            v0 = Ws_[(k0 + 0) * C_H + c]; v1 = Ws_[(k0 + 1) * C_H + c];
            v2 = Ws_[(k0 + 2) * C_H + c]; v3 = Ws_[(k0 + 3) * C_H + c];
            v4 = Ws_[(k0 + 4) * C_H + c]; v5 = Ws_[(k0 + 5) * C_H + c];
            v6 = Ws_[(k0 + 6) * C_H + c]; v7 = Ws_[(k0 + 7) * C_H + c];
            *(float4*)&u.dg.ws[c * 68 + k0]     = make_float4(v0, v1, v2, v3);
            *(float4*)&u.dg.ws[c * 68 + k0 + 4] = make_float4(v4, v5, v6, v7);
            v0 = Wn_[(k0 + 0) * C_H + c]; v1 = Wn_[(k0 + 1) * C_H + c];
            v2 = Wn_[(k0 + 2) * C_H + c]; v3 = Wn_[(k0 + 3) * C_H + c];
            v4 = Wn_[(k0 + 4) * C_H + c]; v5 = Wn_[(k0 + 5) * C_H + c];
            v6 = Wn_[(k0 + 6) * C_H + c]; v7 = Wn_[(k0 + 7) * C_H + c];
            *(float4*)&u.dg.wn[c * 68 + k0]     = make_float4(v0, v1, v2, v3);
            *(float4*)&u.dg.wn[c * 68 + k0 + 4] = make_float4(v4, v5, v6, v7);
        }
        __syncthreads();
        if (npb == 16) {
            const int j0 = jb + w, j1 = jb + 8 + w;
            int q0[KNB], q1[KNB];
            float n0[KNB], n1[KNB];
#pragma unroll
            for (int t = 0; t < KNB; ++t) q0[t] = nbp[j0 * KNB + t];
#pragma unroll
            for (int t = 0; t < KNB; ++t) q1[t] = nbp[j1 * KNB + t];
            float xv0, xv1;
            if (!P.actCoh) {
                xv0 = xin[(size_t)j0 * C_H + lane];
                xv1 = xin[(size_t)j1 * C_H + lane];
#pragma unroll
                for (int t = 0; t < KNB; ++t) n0[t] = xin[(size_t)q0[t] * C_H + lane];
#pragma unroll
                for (int t = 0; t < KNB; ++t) n1[t] = xin[(size_t)q1[t] * C_H + lane];
            } else {
                xv0 = ldc(&xin[(size_t)j0 * C_H + lane]);
                xv1 = ldc(&xin[(size_t)j1 * C_H + lane]);
#pragma unroll
                for (int t = 0; t < KNB; ++t) n0[t] = ldc(&xin[(size_t)q0[t] * C_H + lane]);
#pragma unroll
                for (int t = 0; t < KNB; ++t) n1[t] = ldc(&xin[(size_t)q1[t] * C_H + lane]);
            }
            float a0 = 0.f, a1 = 0.f;
#pragma unroll
            for (int t = 0; t < KNB; ++t) a0 += n0[t];
#pragma unroll
            for (int t = 0; t < KNB; ++t) a1 += n1[t];
            u.dg.xw[2 * w + 0][lane] = xv0;
            u.dg.xw[2 * w + 1][lane] = xv1;
            u.dg.aw[2 * w + 0][lane] = a0 * (1.0f / KNB);
            u.dg.aw[2 * w + 1][lane] = a1 * (1.0f / KNB);
            // per-wave LDS slots: intra-wave ordering only
            float acc0 = bias[l * C_H + lane], acc1 = acc0;
#pragma unroll
            for (int k4 = 0; k4 < C_H / 4; ++k4) {
                float4 x0 = *(const float4*)&u.dg.xw[2 * w + 0][k4 * 4];
                float4 x1 = *(const float4*)&u.dg.xw[2 * w + 1][k4 * 4];
                float4 g0 = *(const float4*)&u.dg.aw[2 * w + 0][k4 * 4];
                float4 g1 = *(const float4*)&u.dg.aw[2 * w + 1][k4 * 4];
                float4 wsv = *(const float4*)&u.dg.ws[lane * 68 + k4 * 4];
                float4 wnv = *(const float4*)&u.dg.wn[lane * 68 + k4 * 4];
                acc0 += x0.x * wsv.x + g0.x * wnv.x;  acc1 += x1.x * wsv.x + g1.x * wnv.x;
                acc0 += x0.y * wsv.y + g0.y * wnv.y;  acc1 += x1.y * wsv.y + g1.y * wnv.y;
                acc0 += x0.z * wsv.z + g0.z * wnv.z;  acc1 += x1.z * wsv.z + g1.z * wnv.z;
                acc0 += x0.w * wsv.w + g0.w * wnv.w;  acc1 += x1.w * wsv.w + g1.w * wnv.w;
            }
            acc0 = fmaxf(acc0, 0.f);
            acc1 = fmaxf(acc1, 0.f);
            if (!last) {
                stc(&xout[(size_t)j0 * C_H + lane], acc0);
                stc(&xout[(size_t)j1 * C_H + lane], acc1);
            } else {
                float v0 = acc0 * head[lane];
                float v1 = acc1 * head[lane];
#pragma unroll
                for (int off = 32; off > 0; off >>= 1) {
                    v0 += __shfl_down(v0, off, 64);
                    v1 += __shfl_down(v1, off, 64);
                }
                if (lane == 0) {
                    float s0v = v0 + hb[0], s1v = v1 + hb[0];
                    if (sdst) { stc(&sdst[j0], s0v); stc(&sdst[j1], s1v); }
                    odst[j0] = 1.f / (1.f + expf(-s0v));   // flushed at kernel end
                    odst[j1] = 1.f / (1.f + expf(-s1v));
                }
            }
        } else {
            const int j = jb + w;
            float xv, a = 0.f;
            if (!P.actCoh) {
                xv = xin[(size_t)j * C_H + lane];
#pragma unroll
                for (int t = 0; t < KNB; ++t) {
                    int q = nbp[j * KNB + t];
                    a += xin[(size_t)q * C_H + lane];
                }
            } else {
                xv = ldc(&xin[(size_t)j * C_H + lane]);
#pragma unroll
                for (int t = 0; t < KNB; ++t) {
                    int q = nbp[j * KNB + t];
                    a += ldc(&xin[(size_t)q * C_H + lane]);
                }
            }
            u.dg.xw[w][lane] = xv;
            u.dg.aw[w][lane] = a * (1.0f / KNB);
            float acc = bias[l * C_H + lane];
#pragma unroll
            for (int k4 = 0; k4 < C_H / 4; ++k4) {
                float4 xv4 = *(const float4*)&u.dg.xw[w][k4 * 4];
                float4 av4 = *(const float4*)&u.dg.aw[w][k4 * 4];
                float4 wsv = *(const float4*)&u.dg.ws[lane * 68 + k4 * 4];
                float4 wnv = *(const float4*)&u.dg.wn[lane * 68 + k4 * 4];
                acc += xv4.x * wsv.x + av4.x * wnv.x;
                acc += xv4.y * wsv.y + av4.y * wnv.y;
                acc += xv4.z * wsv.z + av4.z * wnv.z;
                acc += xv4.w * wsv.w + av4.w * wnv.w;
            }
            acc = fmaxf(acc, 0.f);
            if (!last) {
                stc(&xout[(size_t)j * C_H + lane], acc);
            } else {
                float v = acc * head[lane];
#pragma unroll
                for (int off = 32; off > 0; off >>= 1) v += __shfl_down(v, off, 64);
                if (lane == 0) {
                    float s = v + hb[0];
                    if (sdst) stc(&sdst[j], s);
                    odst[j] = 1.f / (1.f + expf(-s));
                }
            }
        }
    };

    // ---- fused gather + per-row stable top-8; 8 rows/block (NACT blocks) ----
    auto topk = [&](const int* isc, const int* anc, int* indb, int* nbb) {
        __syncthreads();                          // union handoff
        const int b = blk >> 7;                   // branch (128 blocks per branch)
        const int a = anc[b];                     // plain (fresh line)
        const int* row = isc + (size_t)a * N1;
#pragma unroll
        for (int mm = 0; mm < 2; ++mm) {
            int m = mm * BLOCK + tid;
            int pp = row[m];
            u.tk.sx[m] = P.xyz[pp * 3 + 0];
            u.tk.sy[m] = P.xyz[pp * 3 + 1];
            u.tk.sz[m] = P.xyz[pp * 3 + 2];
        }
        if (tid < 8) {
            int grow = blk * 8 + tid;
            stci(&indb[grow], row[grow & (N1 - 1)]);
        }
        __syncthreads();
        {
            const int grow = blk * 8 + w;         // one row per wave
            const int r = grow & (N1 - 1);
            float rx = u.tk.sx[r], ry = u.tk.sy[r], rz = u.tk.sz[r];
            unsigned long long k[16];
#pragma unroll
            for (int t = 0; t < 16; ++t) {
                int m = t * 64 + lane;            // lane-consecutive: conflict-free
                float v = fabsf(rx * u.tk.sx[m] + ry * u.tk.sy[m] + rz * u.tk.sz[m]);
                k[t] = ((unsigned long long)__float_as_uint(v) << 32)
                     | (unsigned int)(0xFFFFFFFFu - (unsigned int)m);
            }
#pragma unroll
            for (int pass = 0; pass < KNB; ++pass) {
                unsigned long long lm = k[0];
#pragma unroll
                for (int t = 1; t < 16; ++t) lm = (k[t] > lm) ? k[t] : lm;
#pragma unroll
                for (int off = 1; off < 64; off <<= 1) {
                    unsigned long long o = __shfl_xor(lm, off, 64);
                    lm = (o > lm) ? o : lm;
                }
                if (lane == 0) {
                    int idx = (int)(0xFFFFFFFFu - (unsigned int)(lm & 0xFFFFFFFFull));
                    stci(&nbb[grow * KNB + pass], b * N1 + idx);
                }
#pragma unroll
                for (int t = 0; t < 16; ++t) if (k[t] == lm) k[t] = 0;
            }
        }
        // publish indb/nbb so this block's own plain reads see them
        asm volatile("s_waitcnt vmcnt(0)" ::: "memory");
        __syncthreads();
    };

    // ===== epoch 1: feat transpose (64 cols/block) + xyz0 gather =====
    if (P.tr) {
        const int g0 = blk * 64;
        const int col = tid & 63, rowH = tid >> 6;
        for (int c0 = 0; c0 < C_IN; c0 += 8) {
            int c = c0 + rowH;
            u.tt[col][c] = P.feat[(size_t)c * N_TOTAL + g0 + col];    // coalesced
        }
        __syncthreads();
        for (int i = tid; i < 64 * C_IN; i += BLOCK) {
            int cc = i >> 7, c = i & 127;
            stc(&P.featT[(size_t)(g0 + cc) * C_IN + c], u.tt[cc][c]); // coalesced
        }
    }
    if (tid < 16) {
        int j = blk * 16 + tid;
        int p = P.ind0[j];
        stc(&P.xyz0[j * 3 + 0], P.xyz[p * 3 + 0]);
        stc(&P.xyz0[j * 3 + 1], P.xyz[p * 3 + 1]);
        stc(&P.xyz0[j * 3 + 2], P.xyz[p * 3 + 2]);
    }
    BAR(1);

    // ===== stage 0 (16 nodes/block, all 512 blocks; 2 nodes/wave) =====
    const int jb0 = blk * 16;
    sphere(16, jb0, P.ind0, P.wsS[0], P.bsS[0], P.xs0[0]);
    BAR(2);
    dgcn(16, jb0, P.xs0[0], P.nb0, P.dgWs[0], P.dgWn[0], P.dgB[0], 0, P.xs0[1], false, nullptr, nullptr, nullptr, nullptr);
    BAR(3);
    dgcn(16, jb0, P.xs0[1], P.nb0, P.dgWs[0], P.dgWn[0], P.dgB[0], 1, P.xs0[2], false, nullptr, nullptr, nullptr, nullptr);
    BAR(4);
    dgcn(16, jb0, P.xs0[2], P.nb0, P.dgWs[0], P.dgWn[0], P.dgB[0], 2, P.xs0[3], false, nullptr, nullptr, nullptr, nullptr);
    BAR(5);
    dgcn(16, jb0, P.xs0[3], P.nb0, P.dgWs[0], P.dgWn[0], P.dgB[0], 3, nullptr, true,
         P.dgH[0], P.dgHb[0], P.s0, P.out);

    // blocks >= NACT: permanently satisfy their slot and exit
    if (blk >= NACT) {
        asm volatile("s_waitcnt vmcnt(0)" ::: "memory");
        __syncthreads();
        if (tid == 0)
            __hip_atomic_store(&P.slot[blk], SLOT_DONE, __ATOMIC_RELAXED,
                               __HIP_MEMORY_SCOPE_AGENT);
        return;
    }
    BAR(6);

    // ===== NMS (block 0 only; s0/xyz0 plain — fresh lines) =====
    if (blk == 0) {
        for (int jj = tid; jj < N0; jj += BLOCK) u.sc[jj] = P.s0[jj];
        __syncthreads();
        for (int it = 0; it < 3; ++it) {
            float bv = -INFINITY; int bi = 0x7fffffff;
            for (int jj = tid; jj < N0; jj += BLOCK) {
                float v = u.sc[jj];
                if (v > bv) { bv = v; bi = jj; }   // strided ascending: first max kept
            }
            rv[tid] = bv; ri[tid] = bi;
            __syncthreads();
            for (int sft = BLOCK / 2; sft > 0; sft >>= 1) {
                if (tid < sft) {
                    float v2 = rv[tid + sft]; int i2 = ri[tid + sft];
                    if (v2 > rv[tid] || (v2 == rv[tid] && i2 < ri[tid])) {
                        rv[tid] = v2; ri[tid] = i2;
                    }
                }
                __syncthreads();
            }
            int sel = ri[0];
            if (tid == 0) {
                stci(&P.anchorA[it], P.ind0[sel]);
                psel[0] = P.xyz0[sel * 3 + 0];
                psel[1] = P.xyz0[sel * 3 + 1];
                psel[2] = P.xyz0[sel * 3 + 2];
            }
            __syncthreads();
            float px = psel[0], py = psel[1], pz = psel[2];
            for (int jj = tid; jj < N0; jj += BLOCK) {
                float d = fabsf(P.xyz0[jj * 3 + 0] * px + P.xyz0[jj * 3 + 1] * py
                              + P.xyz0[jj * 3 + 2] * pz);
                if (d >= COS_T) u.sc[jj] = NEG_INF;
            }
            __syncthreads();
        }
    }
    BAR(7);

    // ===== stages 1 & 2 (384 blocks x 8 nodes; 1 node/wave) =====
    for (int st = 1; st <= 2; ++st) {
        float* const* xb = (st == 1) ? P.xs1 : P.xs2;
        int* indb = (st == 1) ? P.indb1 : P.indb2;
        int* nbb  = (st == 1) ? P.nbb1  : P.nbb2;
        const int* anc = (st == 1) ? P.anchorA : P.anchorB;
        const int ep = (st == 1) ? 7 : 13;
        const int jb12 = blk * 8;

        topk(P.isc[st - 1], anc, indb, nbb);
        sphere(8, jb12, indb, P.wsS[st], P.bsS[st], xb[0]);
        BAR(ep + 1);
        dgcn(8, jb12, xb[0], nbb, P.dgWs[st], P.dgWn[st], P.dgB[st], 0, xb[1], false, nullptr, nullptr, nullptr, nullptr);
        BAR(ep + 2);
        dgcn(8, jb12, xb[1], nbb, P.dgWs[st], P.dgWn[st], P.dgB[st], 1, xb[2], false, nullptr, nullptr, nullptr, nullptr);
        BAR(ep + 3);
        dgcn(8, jb12, xb[2], nbb, P.dgWs[st], P.dgWn[st], P.dgB[st], 2, xb[3], false, nullptr, nullptr, nullptr, nullptr);
        BAR(ep + 4);
        dgcn(8, jb12, xb[3], nbb, P.dgWs[st], P.dgWn[st], P.dgB[st], 3, nullptr, true,
             P.dgH[st], P.dgHb[st], (st == 1) ? P.sbr : nullptr,
             P.out + N0 + (st - 1) * 3 * N1);
        if (st == 1) {
            BAR(12);
            if (blk < 3) {    // per-branch argmax over sbr (plain, fresh)
                float bv = -INFINITY; int bi = 0x7fffffff;
                for (int m = tid; m < N1; m += BLOCK) {
                    float v = P.sbr[blk * N1 + m];
                    if (v > bv) { bv = v; bi = m; }   // ascending: first max kept
                }
                rv[tid] = bv; ri[tid] = bi;
                __syncthreads();
                for (int sft = BLOCK / 2; sft > 0; sft >>= 1) {
                    if (tid < sft) {
                        float v2 = rv[tid + sft]; int i2 = ri[tid + sft];
                        if (v2 > rv[tid] || (v2 == rv[tid] && i2 < ri[tid])) {
                            rv[tid] = v2; ri[tid] = i2;
                        }
                    }
                    __syncthreads();
                }
                if (tid == 0) stci(&P.anchorB[blk], P.indb1[blk * N1 + ri[0]]);
            }
            BAR(13);
        }
    }
}

extern "C" void kernel_launch(void* const* d_in, const int* in_sizes, int n_in,
                              void* d_out, int out_size, void* d_ws, size_t ws_size,
                              hipStream_t stream) {
    MegaParams hp;
    hp.feat = (const float*)d_in[0];
    hp.xyz  = (const float*)d_in[1];
    hp.wsS[0] = (const float*)d_in[2];  hp.bsS[0] = (const float*)d_in[3];
    hp.wsS[1] = (const float*)d_in[4];  hp.bsS[1] = (const float*)d_in[5];
    hp.wsS[2] = (const float*)d_in[6];  hp.bsS[2] = (const float*)d_in[7];
    hp.dgWs[0] = (const float*)d_in[8];  hp.dgWn[0] = (const float*)d_in[9];
    hp.dgB[0]  = (const float*)d_in[10]; hp.dgH[0]  = (const float*)d_in[11];
    hp.dgHb[0] = (const float*)d_in[12];
    hp.dgWs[1] = (const float*)d_in[13]; hp.dgWn[1] = (const float*)d_in[14];
    hp.dgB[1]  = (const float*)d_in[15]; hp.dgH[1]  = (const float*)d_in[16];
    hp.dgHb[1] = (const float*)d_in[17];
    hp.dgWs[2] = (const float*)d_in[18]; hp.dgWn[2] = (const float*)d_in[19];
    hp.dgB[2]  = (const float*)d_in[20]; hp.dgH[2]  = (const float*)d_in[21];
    hp.dgHb[2] = (const float*)d_in[22];
    const int* edge0 = (const int*)d_in[23];
    hp.nb0  = edge0 + N0 * KNB;
    hp.ind0 = (const int*)d_in[24];
    hp.isc[0] = (const int*)d_in[25];
    hp.isc[1] = (const int*)d_in[26];
    hp.out = (float*)d_out;

    float* f = (float*)d_ws;
    size_t o = 0;
    auto takeF = [&](size_t n) { float* p = f + o; o += n; return p; };

    hp.s0   = takeF(N0);
    hp.sbr  = takeF(3 * N1);
    hp.xyz0 = takeF((size_t)N0 * 3);
    o = (o + 63) & ~(size_t)63;
    hp.anchorA = (int*)takeF(64);
    hp.anchorB = (int*)takeF(64);
    hp.indb1 = (int*)takeF(3 * N1);
    hp.nbb1  = (int*)takeF(3 * N1 * KNB);
    hp.indb2 = (int*)takeF(3 * N1);
    hp.nbb2  = (int*)takeF(3 * N1 * KNB);
    o = (o + 63) & ~(size_t)63;
    hp.slot = (unsigned*)takeF(GRID);
    hp.flag = (unsigned*)takeF(8 * 16);
    unsigned* ctrBase = hp.slot;

    size_t needFast = (o + 4 * (size_t)N0 * C_H + 8 * (size_t)(3 * N1) * C_H) * sizeof(float);
    if (ws_size >= needFast) {
        hp.actCoh = 0;
        for (int i = 0; i < 4; ++i) hp.xs0[i] = takeF((size_t)N0 * C_H);
        for (int i = 0; i < 4; ++i) hp.xs1[i] = takeF((size_t)(3 * N1) * C_H);
        for (int i = 0; i < 4; ++i) hp.xs2[i] = takeF((size_t)(3 * N1) * C_H);
    } else {
        hp.actCoh = 1;
        float* xA = takeF((size_t)N0 * C_H);
        float* xB = takeF((size_t)N0 * C_H);
        for (int i = 0; i < 4; ++i) {
            hp.xs0[i] = (i & 1) ? xB : xA;
            hp.xs1[i] = (i & 1) ? xB : xA;
            hp.xs2[i] = (i & 1) ? xB : xA;
        }
    }

    size_t needTr = (o + (size_t)N_TOTAL * C_IN) * sizeof(float);
    if (ws_size >= needTr) {
        hp.tr = 1;
        hp.featT = takeF((size_t)N_TOTAL * C_IN);
    } else {
        hp.tr = 0;
        hp.featT = nullptr;
    }

    hipMemsetAsync((void*)ctrBase, 0, (GRID + 8 * 16) * sizeof(unsigned), stream);
    mega_kernel<<<dim3(GRID), dim3(BLOCK), 0, stream>>>(hp);
}